// Round 4
// baseline (654.979 us; speedup 1.0000x reference)
//
#include <hip/hip_runtime.h>
#include <hip/hip_bf16.h>

// Qwen3 attention block. Round 7: true 8-phase GEMM schedule (m201 port).
//   - gemm_bt_8ph<CT,BM,BN>: BK=64 split into two K-halves in LDS; 4 phases
//     per K-tile, each {1 half-stage prefetch | ds_read subtile | barrier |
//     setprio(1) MFMA setprio(0) | barrier}; counted vmcnt only at ph1/ph3
//     exits (3AI+2BI steady, exact tail counts); all-wave landing guarantees
//     at vmcnt->barrier points; chunk-XOR swizzle (c ^ (r&3) ^ ((r>>2)&3))
//     via pre-swizzled global source (free 2-way aliasing only).
//   - QKV: 256x256 (192 blocks); Wo: 256x128 (256 blocks, full CU fill).
// Flash attention / conversions / rmsnorm unchanged (verified round 5).
// B=1, S=2048, HIDDEN=4096, NQ=32, NKV=8 (GQA R=4), HD=128.

#define S_LEN   2048
#define HIDDEN  4096
#define NQ      32
#define NKV     8
#define HD      128
#define QKV_DIM 6144      // (NQ + 2*NKV) * HD
#define NQHD    4096      // NQ * HD
#define K_OFF   4096
#define V_OFF   5120
#define EPSF    1e-6f

typedef _Float16 half8 __attribute__((ext_vector_type(8)));
typedef _Float16 half4v __attribute__((ext_vector_type(4)));
typedef _Float16 half2v __attribute__((ext_vector_type(2)));
typedef float floatx4 __attribute__((ext_vector_type(4)));

__device__ __forceinline__ void gload_lds16(const void* g, void* l) {
    __builtin_amdgcn_global_load_lds(
        (const __attribute__((address_space(1))) unsigned int*)g,
        (__attribute__((address_space(3))) unsigned int*)l, 16, 0, 0);
}

template <int N> __device__ __forceinline__ void vwait_bar() {
    if constexpr (N == 0)
        asm volatile("s_waitcnt vmcnt(0)\n\ts_barrier" ::: "memory");
    else if constexpr (N == 3)
        asm volatile("s_waitcnt vmcnt(3)\n\ts_barrier" ::: "memory");
    else if constexpr (N == 4)
        asm volatile("s_waitcnt vmcnt(4)\n\ts_barrier" ::: "memory");
    else if constexpr (N == 6)
        asm volatile("s_waitcnt vmcnt(6)\n\ts_barrier" ::: "memory");
    else if constexpr (N == 8)
        asm volatile("s_waitcnt vmcnt(8)\n\ts_barrier" ::: "memory");
    else
        asm volatile("s_waitcnt vmcnt(10)\n\ts_barrier" ::: "memory");
}

#define PHB asm volatile("s_barrier" ::: "memory")

// ---------------------------------------------------------------------------
// fp32 -> fp16 elementwise convert (8 elems/thread)
// ---------------------------------------------------------------------------
__global__ __launch_bounds__(256) void conv_f32_f16(const float* __restrict__ src,
                                                    _Float16* __restrict__ dst) {
    const size_t i = ((size_t)blockIdx.x * 256 + threadIdx.x) * 8;
    float4 a = *(const float4*)(src + i);
    float4 b = *(const float4*)(src + i + 4);
    half8 h;
    h[0] = (_Float16)a.x; h[1] = (_Float16)a.y; h[2] = (_Float16)a.z; h[3] = (_Float16)a.w;
    h[4] = (_Float16)b.x; h[5] = (_Float16)b.y; h[6] = (_Float16)b.z; h[7] = (_Float16)b.w;
    *(half8*)(dst + i) = h;
}

// ---------------------------------------------------------------------------
// W[K][N] fp32 -> Wt[N][K] fp16 (transpose + convert), 64x64 tiles via LDS.
// ---------------------------------------------------------------------------
__global__ __launch_bounds__(256) void conv_w_transpose(const float* __restrict__ src,
                                                        _Float16* __restrict__ dst,
                                                        int N, int K) {
    __shared__ float T[64][65];
    const int tid = threadIdx.x;
    const int n0 = blockIdx.x * 64, k0 = blockIdx.y * 64;
    const int rr = tid >> 4, cc = (tid & 15) * 4;
    #pragma unroll
    for (int l = 0; l < 4; ++l) {
        const int r = rr + l * 16;
        *(float4*)&T[r][cc] = *(const float4*)(src + (size_t)(k0 + r) * N + n0 + cc);
    }
    __syncthreads();
    #pragma unroll
    for (int l = 0; l < 4; ++l) {
        const int rn = rr + l * 16;
        half4v h;
        h[0] = (_Float16)T[cc + 0][rn];
        h[1] = (_Float16)T[cc + 1][rn];
        h[2] = (_Float16)T[cc + 2][rn];
        h[3] = (_Float16)T[cc + 3][rn];
        *(half4v*)(dst + (size_t)(n0 + rn) * K + k0 + cc) = h;
    }
}

// ---------------------------------------------------------------------------
// 8-phase GEMM: C[M][ldc] = A[M][K] @ Bt[N][K]^T, fp16 in, CT out.
// BM x BN tile, BK=64 as two K-halves, 512 threads = 8 waves (2M x BN/64 N..
// fixed 2x4), per-wave BM/2 x BN/4 output. 4 phases per K-tile; 1 half-stage
// prefetch per phase; counted vmcnt at ph1/ph3 exits only.
// ---------------------------------------------------------------------------
#define MFMA_PH(NB)                                                            \
    __builtin_amdgcn_s_setprio(1);                                             \
    _Pragma("unroll")                                                          \
    for (int mt = 0; mt < MI; ++mt)                                            \
        _Pragma("unroll")                                                      \
        for (int j = 0; j < NP; ++j)                                           \
            acc[mt][(NB) + j] = __builtin_amdgcn_mfma_f32_16x16x32_f16(        \
                af[mt], bf[j], acc[mt][(NB) + j], 0, 0, 0);                    \
    __builtin_amdgcn_s_setprio(0);

#define GEMM_TILE(KT, ST1, ST2, V1, V3)                                        \
  {                                                                            \
    const int cur_ = (KT) & 1;                                                 \
    const char* bA0_ = (const char*)&sA[cur_][0][0] + rowA_ + csw;             \
    const char* bA1_ = (const char*)&sA[cur_][1][0] + rowA_ + csw;             \
    const char* bB0_ = (const char*)&sB[cur_][0][0] + rowB_ + csw;             \
    const char* bB1_ = (const char*)&sB[cur_][1][0] + rowB_ + csw;             \
    half8 af[MI]; half8 bf[NP];                                                \
    /* ---- ph0: ks0, n-lo ---- */                                             \
    if (ST1) stageB(cur_ ^ 1, (KT) + 1, 1);                                    \
    _Pragma("unroll") for (int mt = 0; mt < MI; ++mt)                          \
        af[mt] = *(const half8*)(bA0_ + mt * 1024);                            \
    _Pragma("unroll") for (int j = 0; j < NP; ++j)                             \
        bf[j] = *(const half8*)(bB0_ + j * 1024);                              \
    PHB;                                                                       \
    MFMA_PH(0)                                                                 \
    PHB;                                                                       \
    /* ---- ph1: ks0, n-hi ---- */                                             \
    if (ST2) stageA(cur_, (KT) + 2, 0);                                        \
    _Pragma("unroll") for (int j = 0; j < NP; ++j)                             \
        bf[j] = *(const half8*)(bB0_ + (NP + j) * 1024);                       \
    PHB;                                                                       \
    MFMA_PH(NP)                                                                \
    vwait_bar<V1>();                                                           \
    /* ---- ph2: ks1, n-lo ---- */                                             \
    if (ST2) stageB(cur_, (KT) + 2, 0);                                        \
    _Pragma("unroll") for (int mt = 0; mt < MI; ++mt)                          \
        af[mt] = *(const half8*)(bA1_ + mt * 1024);                            \
    _Pragma("unroll") for (int j = 0; j < NP; ++j)                             \
        bf[j] = *(const half8*)(bB1_ + j * 1024);                              \
    PHB;                                                                       \
    MFMA_PH(0)                                                                 \
    PHB;                                                                       \
    /* ---- ph3: ks1, n-hi ---- */                                             \
    if (ST2) stageA(cur_, (KT) + 2, 1);                                        \
    _Pragma("unroll") for (int j = 0; j < NP; ++j)                             \
        bf[j] = *(const half8*)(bB1_ + (NP + j) * 1024);                       \
    PHB;                                                                       \
    MFMA_PH(NP)                                                                \
    vwait_bar<V3>();                                                           \
  }

template <typename CT, int BM, int BN>
__global__ __launch_bounds__(512, 2) void gemm_bt_8ph(const _Float16* __restrict__ A,
                                                      const _Float16* __restrict__ Bt,
                                                      CT* __restrict__ C,
                                                      int K, int ldc) {
    constexpr int AI = BM / 128;        // A gload_lds per wave per half-stage
    constexpr int BI = BN / 128;        // B gload_lds per wave per half-stage
    constexpr int MI = BM / 32;         // m-frags per wave
    constexpr int NI = BN / 64;         // n-frags per wave
    constexpr int NP = NI / 2;          // n-frags per phase
    constexpr int VNS = 3 * AI + 2 * BI;        // steady-state vmcnt
    constexpr int VT1 = 2 * AI + 2 * BI;        // kt = NT-2, ph1 exit
    constexpr int VT3 = AI + BI;                // kt = NT-2, ph3 exit

    __shared__ _Float16 sA[2][2][BM * 32];      // [dbuf][khalf][row*32]
    __shared__ _Float16 sB[2][2][BN * 32];

    const int tid = threadIdx.x;
    const int wave = tid >> 6, lane = tid & 63;
    const int fl = lane & 15, quad = lane >> 4;
    const int wm = (wave >> 2) * (BM / 2);
    const int wn = (wave & 3) * (BN / 4);

    // bijective XCD swizzle (nwg % 8 == 0 for our grids)
    const int nwg = gridDim.x * gridDim.y;
    int bid = blockIdx.y * gridDim.x + blockIdx.x;
    bid = (bid & 7) * (nwg >> 3) + (bid >> 3);
    const int m0 = (bid / gridDim.x) * BM;
    const int n0 = (bid % gridDim.x) * BN;

    // staging lane geometry: lane covers row rl = lane>>2 (of 16), 16B chunk
    // lane&3; SOURCE k-chunk pre-swizzled so LDS stays linear (rule #21).
    const int rl = lane >> 2;
    const int gch = (((lane & 3) ^ (rl & 3) ^ ((rl >> 2) & 3))) * 8; // halves
    // ds_read swizzled chunk byte offset (uniform per lane for all frags)
    const int csw = ((quad ^ (fl & 3) ^ ((fl >> 2) & 3))) * 16;      // bytes
    const int rowA_ = (wm + fl) * 64;
    const int rowB_ = (wn + fl) * 64;

    auto stageA = [&](int buf, int T, int h) {
        const _Float16* src = A + (size_t)(m0 + wave * 16 + rl) * K
                              + T * 64 + h * 32 + gch;
        _Float16* dst = &sA[buf][h][wave * 16 * 32];
        #pragma unroll
        for (int i = 0; i < AI; ++i)
            gload_lds16(src + (size_t)(i * 128) * K, dst + i * 128 * 32);
    };
    auto stageB = [&](int buf, int T, int h) {
        const _Float16* src = Bt + (size_t)(n0 + wave * 16 + rl) * K
                              + T * 64 + h * 32 + gch;
        _Float16* dst = &sB[buf][h][wave * 16 * 32];
        #pragma unroll
        for (int i = 0; i < BI; ++i)
            gload_lds16(src + (size_t)(i * 128) * K, dst + i * 128 * 32);
    };

    floatx4 acc[MI][NI] = {};

    // prologue: tiles 0,1 except B1.kh1 (staged at kt=0.ph0). Order matters:
    // A0h0, B0h0, A0h1, B0h1, A1h0, B1h0, A1h1 -> vmcnt(VNS) leaves exactly
    // the last 5 half-stages outstanding (A0h0+B0h0 landed).
    stageA(0, 0, 0);
    stageB(0, 0, 0);
    stageA(0, 0, 1);
    stageB(0, 0, 1);
    stageA(1, 1, 0);
    stageB(1, 1, 0);
    stageA(1, 1, 1);
    vwait_bar<VNS>();

    const int NT = K >> 6;
    for (int kt = 0; kt < NT - 2; ++kt)
        GEMM_TILE(kt, true, true, VNS, VNS)
    GEMM_TILE(NT - 2, true, false, VT1, VT3)
    GEMM_TILE(NT - 1, false, false, 0, 0)

    #pragma unroll
    for (int mi = 0; mi < MI; ++mi)
        #pragma unroll
        for (int ni = 0; ni < NI; ++ni)
            #pragma unroll
            for (int r = 0; r < 4; ++r)
                C[(size_t)(m0 + wm + mi * 16 + quad * 4 + r) * ldc
                  + n0 + wn + ni * 16 + fl] = (CT)acc[mi][ni][r];
}

#undef GEMM_TILE
#undef MFMA_PH

// ---------------------------------------------------------------------------
// Fused RMSNorm + RoPE, in-place on fp16 qkv (fp32 math).
// ---------------------------------------------------------------------------
__global__ __launch_bounds__(128) void rmsnorm_rope16(_Float16* __restrict__ qkv,
                                                      const float* __restrict__ qg,
                                                      const float* __restrict__ kg,
                                                      const float* __restrict__ cosb,
                                                      const float* __restrict__ sinb) {
    const int h = blockIdx.x;   // 0..39
    const int s = blockIdx.y;   // 0..2047
    const int d = threadIdx.x;  // 0..127
    const bool isq = (h < NQ);
    const int off = isq ? h * HD : K_OFF + (h - NQ) * HD;
    _Float16* base = qkv + (size_t)s * QKV_DIM + off;

    float x = (float)base[d];
    float ss = x * x;
    #pragma unroll
    for (int o = 32; o; o >>= 1) ss += __shfl_xor(ss, o);

    __shared__ float red[2];
    __shared__ float sh[HD];
    if ((d & 63) == 0) red[d >> 6] = ss;
    __syncthreads();
    float tot = red[0] + red[1];
    float rms = rsqrtf(tot * (1.0f / (float)HD) + EPSF);
    const float* gamma = isq ? qg : kg;
    float xn = x * rms * gamma[d];
    sh[d] = xn;
    __syncthreads();

    float out;
    if (d < 64) {
        float c = cosb[s * 64 + d], sn = sinb[s * 64 + d];
        out = xn * c - sh[d + 64] * sn;
    } else {
        int j = d - 64;
        float c = cosb[s * 64 + j], sn = sinb[s * 64 + j];
        out = xn * c + sh[d - 64] * sn;
    }
    base[d] = (_Float16)out;
}

// ---------------------------------------------------------------------------
// GQA-shared flash attention, fp16 MFMA (verified round 5).
// ---------------------------------------------------------------------------
#define FAM 32     // q rows per wave
#define FAN 64     // kv tile rows
#define LQK 136    // Ks row stride (halves)
#define LVP 68     // Vt/Ps row stride (halves)

__global__ __launch_bounds__(256, 2) void flash_attn_gqa(
        const _Float16* __restrict__ qkv, _Float16* __restrict__ attn) {
    __shared__ __align__(16) _Float16 Ks[FAN][LQK];
    __shared__ __align__(16) _Float16 Vt[HD][LVP];
    __shared__ __align__(16) _Float16 Ps[4][FAM][LVP];

    const int tid = threadIdx.x;
    const int wave = tid >> 6, lane = tid & 63;
    const int fl = lane & 15, quad = lane >> 4;

    const int bd = blockIdx.x;
    const int c = bd & 255, sflip = bd >> 8;
    const int qt = sflip ? 63 - (c & 63) : (c & 63);
    const int kvh = (sflip << 2) + (c >> 6);
    const int h = kvh * 4 + wave;
    const int m0 = qt * FAM;
    const float scale = 0.08838834764831845f;  // HD^-0.5

    half8 qf[2][4];
    #pragma unroll
    for (int mt = 0; mt < 2; ++mt)
        #pragma unroll
        for (int ks = 0; ks < 4; ++ks)
            qf[mt][ks] = *(const half8*)(qkv
                + (size_t)(m0 + mt * 16 + fl) * QKV_DIM + h * HD + ks * 32 + quad * 8);

    float m_prev[2][4], l_prev[2][4];
    #pragma unroll
    for (int mt = 0; mt < 2; ++mt)
        #pragma unroll
        for (int r = 0; r < 4; ++r) { m_prev[mt][r] = -1e30f; l_prev[mt][r] = 0.f; }
    floatx4 oacc[2][8] = {};

    const int tmax = (m0 + FAM - 1) / FAN;
    for (int t = 0; t <= tmax; ++t) {
        const int n0 = t * FAN;
        __syncthreads();   // (A) all waves done reading prev Ks/Vt

        #pragma unroll
        for (int l = 0; l < 4; ++l) {
            const int f = tid + l * 256;
            const int r = f >> 4, c8 = (f & 15) * 8;
            *(half8*)&Ks[r][c8] = *(const half8*)(qkv
                + (size_t)(n0 + r) * QKV_DIM + K_OFF + kvh * HD + c8);
        }
        {
            const int p = tid & 31, g0 = tid >> 5;
            #pragma unroll
            for (int gi = 0; gi < 2; ++gi) {
                const int g = g0 + gi * 8;
                const _Float16* v0p = qkv + (size_t)(n0 + 2 * p) * QKV_DIM
                                      + V_OFF + kvh * HD + 8 * g;
                half8 va = *(const half8*)v0p;
                half8 vb = *(const half8*)(v0p + QKV_DIM);
                #pragma unroll
                for (int i = 0; i < 8; ++i) {
                    half2v hh; hh[0] = va[i]; hh[1] = vb[i];
                    *(half2v*)&Vt[8 * g + i][2 * p] = hh;
                }
            }
        }
        __syncthreads();   // (B) tiles staged

        floatx4 sacc[2][4] = {};
        __builtin_amdgcn_s_setprio(1);
        #pragma unroll
        for (int ks = 0; ks < 4; ++ks)
            #pragma unroll
            for (int nt = 0; nt < 4; ++nt) {
                half8 bf = *(const half8*)&Ks[nt * 16 + fl][ks * 32 + quad * 8];
                sacc[0][nt] = __builtin_amdgcn_mfma_f32_16x16x32_f16(
                    qf[0][ks], bf, sacc[0][nt], 0, 0, 0);
                sacc[1][nt] = __builtin_amdgcn_mfma_f32_16x16x32_f16(
                    qf[1][ks], bf, sacc[1][nt], 0, 0, 0);
            }
        __builtin_amdgcn_s_setprio(0);

        const bool diag = (t == tmax);
        float mx[2][4];
        #pragma unroll
        for (int mt = 0; mt < 2; ++mt)
            #pragma unroll
            for (int r = 0; r < 4; ++r) mx[mt][r] = -1e30f;
        #pragma unroll
        for (int mt = 0; mt < 2; ++mt)
            #pragma unroll
            for (int nt = 0; nt < 4; ++nt)
                #pragma unroll
                for (int r = 0; r < 4; ++r) {
                    float sv = sacc[mt][nt][r] * scale;
                    if (diag && (n0 + nt * 16 + fl > m0 + mt * 16 + quad * 4 + r))
                        sv = -1e30f;
                    sacc[mt][nt][r] = sv;
                    mx[mt][r] = fmaxf(mx[mt][r], sv);
                }
        #pragma unroll
        for (int mt = 0; mt < 2; ++mt)
            #pragma unroll
            for (int r = 0; r < 4; ++r)
                #pragma unroll
                for (int o = 8; o; o >>= 1)
                    mx[mt][r] = fmaxf(mx[mt][r], __shfl_xor(mx[mt][r], o));

        float alpha[2][4], rs[2][4];
        #pragma unroll
        for (int mt = 0; mt < 2; ++mt)
            #pragma unroll
            for (int r = 0; r < 4; ++r) {
                float nm = fmaxf(m_prev[mt][r], mx[mt][r]);
                alpha[mt][r] = __expf(m_prev[mt][r] - nm);
                m_prev[mt][r] = nm;
                rs[mt][r] = 0.f;
            }
        #pragma unroll
        for (int mt = 0; mt < 2; ++mt)
            #pragma unroll
            for (int nt = 0; nt < 4; ++nt)
                #pragma unroll
                for (int r = 0; r < 4; ++r) {
                    float p = __expf(sacc[mt][nt][r] - m_prev[mt][r]);
                    rs[mt][r] += p;
                    Ps[wave][mt * 16 + quad * 4 + r][nt * 16 + fl] = (_Float16)p;
                }
        #pragma unroll
        for (int mt = 0; mt < 2; ++mt)
            #pragma unroll
            for (int r = 0; r < 4; ++r) {
                #pragma unroll
                for (int o = 8; o; o >>= 1) rs[mt][r] += __shfl_xor(rs[mt][r], o);
                l_prev[mt][r] = l_prev[mt][r] * alpha[mt][r] + rs[mt][r];
            }
        #pragma unroll
        for (int mt = 0; mt < 2; ++mt)
            #pragma unroll
            for (int dt = 0; dt < 8; ++dt)
                #pragma unroll
                for (int r = 0; r < 4; ++r) oacc[mt][dt][r] *= alpha[mt][r];

        __builtin_amdgcn_s_setprio(1);
        #pragma unroll
        for (int ks2 = 0; ks2 < 2; ++ks2) {
            half8 pa[2];
            #pragma unroll
            for (int mt = 0; mt < 2; ++mt) {
                half4v plo = *(const half4v*)&Ps[wave][mt * 16 + fl][ks2 * 32 + quad * 8];
                half4v phi = *(const half4v*)&Ps[wave][mt * 16 + fl][ks2 * 32 + quad * 8 + 4];
                pa[mt] = __builtin_shufflevector(plo, phi, 0, 1, 2, 3, 4, 5, 6, 7);
            }
            #pragma unroll
            for (int dt = 0; dt < 8; ++dt) {
                half4v vlo = *(const half4v*)&Vt[dt * 16 + fl][ks2 * 32 + quad * 8];
                half4v vhi = *(const half4v*)&Vt[dt * 16 + fl][ks2 * 32 + quad * 8 + 4];
                half8 vb = __builtin_shufflevector(vlo, vhi, 0, 1, 2, 3, 4, 5, 6, 7);
                oacc[0][dt] = __builtin_amdgcn_mfma_f32_16x16x32_f16(
                    pa[0], vb, oacc[0][dt], 0, 0, 0);
                oacc[1][dt] = __builtin_amdgcn_mfma_f32_16x16x32_f16(
                    pa[1], vb, oacc[1][dt], 0, 0, 0);
            }
        }
        __builtin_amdgcn_s_setprio(0);
    }

    #pragma unroll
    for (int mt = 0; mt < 2; ++mt) {
        float linv[4];
        #pragma unroll
        for (int r = 0; r < 4; ++r) linv[r] = 1.0f / l_prev[mt][r];
        #pragma unroll
        for (int dt = 0; dt < 8; ++dt)
            #pragma unroll
            for (int r = 0; r < 4; ++r)
                attn[(size_t)(m0 + mt * 16 + quad * 4 + r) * NQHD
                     + h * HD + dt * 16 + fl] = (_Float16)(oacc[mt][dt][r] * linv[r]);
    }
}

// ---------------------------------------------------------------------------
extern "C" void kernel_launch(void* const* d_in, const int* in_sizes, int n_in,
                              void* d_out, int out_size, void* d_ws, size_t ws_size,
                              hipStream_t stream) {
    // inputs: positions, hidden_states, Wqkv, Wo, q_gamma, k_gamma, cos, sin
    const float* hidden = (const float*)d_in[1];
    const float* Wqkv   = (const float*)d_in[2];
    const float* Wo     = (const float*)d_in[3];
    const float* qg     = (const float*)d_in[4];
    const float* kg     = (const float*)d_in[5];
    const float* cosb   = (const float*)d_in[6];
    const float* sinb   = (const float*)d_in[7];
    float* out = (float*)d_out;

    // ws layout (67.1 MB total):
    //   buf0: h16 [2048][4096]     -> later attn16 [2048][4096] (same size)
    //   buf1: wT  [6144][4096]     -> later woT [4096][4096] (smaller)
    // qkv16 [2048][6144] fp16 lives in d_out; dead before gemm2 overwrites it.
    _Float16* buf0  = (_Float16*)d_ws;
    _Float16* wT    = buf0 + (size_t)S_LEN * HIDDEN;
    _Float16* qkv16 = (_Float16*)d_out;
    _Float16* attn16 = buf0;

    // 1) convert hidden -> fp16
    conv_f32_f16<<<(S_LEN * HIDDEN) / 2048, 256, 0, stream>>>(hidden, buf0);
    // 2) Wqkv [K=4096][N=6144] -> wT [6144][4096] fp16
    conv_w_transpose<<<dim3(QKV_DIM / 64, HIDDEN / 64), 256, 0, stream>>>(
        Wqkv, wT, QKV_DIM, HIDDEN);
    // 3) qkv16 = h16 @ wT^T  (256x256 tiles, 24x8 = 192 blocks)
    gemm_bt_8ph<_Float16, 256, 256><<<dim3(QKV_DIM / 256, S_LEN / 256), 512, 0, stream>>>(
        buf0, wT, qkv16, HIDDEN, QKV_DIM);
    // 4) RMSNorm + RoPE in place (fp16)
    rmsnorm_rope16<<<dim3(NQ + NKV, S_LEN), 128, 0, stream>>>(qkv16, qg, kg, cosb, sinb);
    // 5) GQA-shared flash attention -> attn16 (buf0; h16 dead)
    flash_attn_gqa<<<dim3((S_LEN / FAM) * NKV), 256, 0, stream>>>(qkv16, attn16);
    // 6) Wo [4096][4096] -> woT fp16 (reuses wT slot; Wqkv16 dead)
    conv_w_transpose<<<dim3(HIDDEN / 64, NQHD / 64), 256, 0, stream>>>(
        Wo, wT, HIDDEN, NQHD);
    // 7) out = attn16 @ woT^T  (256x128 tiles, 32x8 = 256 blocks, full fill)
    gemm_bt_8ph<float, 256, 128><<<dim3(HIDDEN / 128, S_LEN / 256), 512, 0, stream>>>(
        attn16, wT, out, NQHD, HIDDEN);
}

// Round 5
// 574.161 us; speedup vs baseline: 1.1408x; 1.1408x over previous
//
#include <hip/hip_runtime.h>
#include <hip/hip_bf16.h>

// Qwen3 attention block. Round 8: synthesis of rounds 5/6 GEMM evidence.
//   - gemm_bt_db<CT>: 128x128 tile, BK=64, 4 waves (2x2 of 64x64), LDS
//     double-buffer (64 KiB -> 2 blocks/CU), counted vmcnt(8) (never 0 in
//     main loop), round-6's PROVEN zero-conflict swizzle (128B rows,
//     chunk = (lane&7)^row&7 on the pre-swizzled global source, read back
//     with chunk = quad^(fl&7)). No XCD swizzle (round-5 order fetched less).
//     k-accumulation order identical to rounds 5-7.
//   - rmsnorm_rope_w: one wave per head, lane l owns (x[l], x[l+64]) so the
//     RoPE pair is lane-local; RMS via pure shfl; no LDS/barriers;
//     2048 blocks instead of 81920.
// Flash attention / conversions unchanged (verified round 5).
// B=1, S=2048, HIDDEN=4096, NQ=32, NKV=8 (GQA R=4), HD=128.

#define S_LEN   2048
#define HIDDEN  4096
#define NQ      32
#define NKV     8
#define HD      128
#define QKV_DIM 6144      // (NQ + 2*NKV) * HD
#define NQHD    4096      // NQ * HD
#define K_OFF   4096
#define V_OFF   5120
#define EPSF    1e-6f

typedef _Float16 half8 __attribute__((ext_vector_type(8)));
typedef _Float16 half4v __attribute__((ext_vector_type(4)));
typedef _Float16 half2v __attribute__((ext_vector_type(2)));
typedef float floatx4 __attribute__((ext_vector_type(4)));

__device__ __forceinline__ void gload_lds16(const void* g, void* l) {
    __builtin_amdgcn_global_load_lds(
        (const __attribute__((address_space(1))) unsigned int*)g,
        (__attribute__((address_space(3))) unsigned int*)l, 16, 0, 0);
}

// ---------------------------------------------------------------------------
// fp32 -> fp16 elementwise convert (8 elems/thread)
// ---------------------------------------------------------------------------
__global__ __launch_bounds__(256) void conv_f32_f16(const float* __restrict__ src,
                                                    _Float16* __restrict__ dst) {
    const size_t i = ((size_t)blockIdx.x * 256 + threadIdx.x) * 8;
    float4 a = *(const float4*)(src + i);
    float4 b = *(const float4*)(src + i + 4);
    half8 h;
    h[0] = (_Float16)a.x; h[1] = (_Float16)a.y; h[2] = (_Float16)a.z; h[3] = (_Float16)a.w;
    h[4] = (_Float16)b.x; h[5] = (_Float16)b.y; h[6] = (_Float16)b.z; h[7] = (_Float16)b.w;
    *(half8*)(dst + i) = h;
}

// ---------------------------------------------------------------------------
// W[K][N] fp32 -> Wt[N][K] fp16 (transpose + convert), 64x64 tiles via LDS.
// ---------------------------------------------------------------------------
__global__ __launch_bounds__(256) void conv_w_transpose(const float* __restrict__ src,
                                                        _Float16* __restrict__ dst,
                                                        int N, int K) {
    __shared__ float T[64][65];
    const int tid = threadIdx.x;
    const int n0 = blockIdx.x * 64, k0 = blockIdx.y * 64;
    const int rr = tid >> 4, cc = (tid & 15) * 4;
    #pragma unroll
    for (int l = 0; l < 4; ++l) {
        const int r = rr + l * 16;
        *(float4*)&T[r][cc] = *(const float4*)(src + (size_t)(k0 + r) * N + n0 + cc);
    }
    __syncthreads();
    #pragma unroll
    for (int l = 0; l < 4; ++l) {
        const int rn = rr + l * 16;
        half4v h;
        h[0] = (_Float16)T[cc + 0][rn];
        h[1] = (_Float16)T[cc + 1][rn];
        h[2] = (_Float16)T[cc + 2][rn];
        h[3] = (_Float16)T[cc + 3][rn];
        *(half4v*)(dst + (size_t)(n0 + rn) * K + k0 + cc) = h;
    }
}

// ---------------------------------------------------------------------------
// Double-buffered GEMM: C[M][ldc] = A[M][K] @ Bt[N][K]^T, fp16 in, CT out.
// 128x128 tile, BK=64, 256 threads = 4 waves (2x2), per-wave 64x64 (4x4 MFMA).
// LDS rows are 64 halves (128 B); staging source pre-swizzled so LDS stays
// linear: LDS[r][c] holds global chunk c^(r&7) of row r (16B chunks).
// Fragment reads use chunk quad^(fl&7) -> global chunk quad; round 6
// measured ZERO bank conflicts with this exact pattern.
// ---------------------------------------------------------------------------
template <typename CT>
__global__ __launch_bounds__(256, 2) void gemm_bt_db(const _Float16* __restrict__ A,
                                                     const _Float16* __restrict__ Bt,
                                                     CT* __restrict__ C,
                                                     int K, int ldc) {
    __shared__ _Float16 sA[2][128 * 64];   // 32 KiB
    __shared__ _Float16 sB[2][128 * 64];   // 32 KiB

    const int tid = threadIdx.x;
    const int wave = tid >> 6, lane = tid & 63;
    const int fl = lane & 15, quad = lane >> 4;
    const int m0 = blockIdx.y * 128, n0 = blockIdx.x * 128;
    const int wm = (wave >> 1) * 64, wn = (wave & 1) * 64;

    // staging: per gload_lds, 64 lanes cover 8 rows x 8 chunks of 16B.
    const int srow = lane >> 3;                  // row within 8-row group
    const int sch  = ((lane & 7) ^ srow) * 8;    // pre-swizzled source chunk (halves)

    auto stage = [&](int p, int kt) {
        const int kb = kt * 64;
        #pragma unroll
        for (int i = 0; i < 4; ++i) {
            const int r0 = i * 32 + wave * 8;    // waves cover rows 0..127
            gload_lds16(A + (size_t)(m0 + r0 + srow) * K + kb + sch,
                        &sA[p][r0 * 64]);
            gload_lds16(Bt + (size_t)(n0 + r0 + srow) * K + kb + sch,
                        &sB[p][r0 * 64]);
        }
    };

    floatx4 acc[4][4] = {};

    stage(0, 0);
    stage(1, 1);

    // fragment-read swizzled chunk byte offsets (row&7 == fl&7 for all frags)
    const int cs0 = (quad ^ (fl & 7)) << 4;
    const int cs1 = ((4 + quad) ^ (fl & 7)) << 4;

    const int NT = K >> 6;
    for (int t = 0; t < NT; ++t) {
        // every wave confirms its own tile-t loads landed, then barrier =>
        // all waves' tile-t loads landed. Never vmcnt(0) in steady state.
        if (t == NT - 1)
            asm volatile("s_waitcnt vmcnt(0)\n\ts_barrier" ::: "memory");
        else
            asm volatile("s_waitcnt vmcnt(8)\n\ts_barrier" ::: "memory");

        const char* Ab = (const char*)&sA[t & 1][0];
        const char* Bb = (const char*)&sB[t & 1][0];

        #pragma unroll
        for (int ks = 0; ks < 2; ++ks) {
            const int cs = ks ? cs1 : cs0;
            half8 af[4], bf[4];
            #pragma unroll
            for (int x = 0; x < 4; ++x) {
                af[x] = *(const half8*)(Ab + (wm + x * 16 + fl) * 128 + cs);
                bf[x] = *(const half8*)(Bb + (wn + x * 16 + fl) * 128 + cs);
            }
            __builtin_amdgcn_s_setprio(1);
            #pragma unroll
            for (int i = 0; i < 4; ++i)
                #pragma unroll
                for (int j = 0; j < 4; ++j)
                    acc[i][j] = __builtin_amdgcn_mfma_f32_16x16x32_f16(
                        af[i], bf[j], acc[i][j], 0, 0, 0);
            __builtin_amdgcn_s_setprio(0);
        }

        // all waves' LDS reads for tile t retired (consumed before barrier);
        // safe to refill this buffer with tile t+2.
        asm volatile("s_barrier" ::: "memory");
        if (t + 2 < NT) stage(t & 1, t + 2);
    }

    #pragma unroll
    for (int i = 0; i < 4; ++i)
        #pragma unroll
        for (int j = 0; j < 4; ++j)
            #pragma unroll
            for (int r = 0; r < 4; ++r)
                C[(size_t)(m0 + wm + i * 16 + quad * 4 + r) * ldc
                  + n0 + wn + j * 16 + fl] = (CT)acc[i][j][r];
}

// ---------------------------------------------------------------------------
// Fused RMSNorm + RoPE, wave-per-head. Lane l owns (x[l], x[l+64]) so the
// RoPE pair is lane-local; RMS sum is a pure 64-lane shfl reduction.
// Grid: S_LEN blocks x 256 threads (4 waves loop over 40 heads).
// ---------------------------------------------------------------------------
__global__ __launch_bounds__(256) void rmsnorm_rope_w(_Float16* __restrict__ qkv,
                                                      const float* __restrict__ qg,
                                                      const float* __restrict__ kg,
                                                      const float* __restrict__ cosb,
                                                      const float* __restrict__ sinb) {
    const int s = blockIdx.x;
    const int wave = threadIdx.x >> 6, lane = threadIdx.x & 63;
    const float c  = cosb[s * 64 + lane];
    const float sn = sinb[s * 64 + lane];

    #pragma unroll
    for (int hi = 0; hi < 10; ++hi) {
        const int h = hi * 4 + wave;   // 0..39
        const bool isq = (h < NQ);
        _Float16* base = qkv + (size_t)s * QKV_DIM
                         + (isq ? h * HD : K_OFF + (h - NQ) * HD);
        float x1 = (float)base[lane];
        float x2 = (float)base[lane + 64];
        float ss = x1 * x1 + x2 * x2;
        #pragma unroll
        for (int o = 32; o; o >>= 1) ss += __shfl_xor(ss, o);
        float rms = rsqrtf(ss * (1.0f / (float)HD) + EPSF);
        const float* g = isq ? qg : kg;
        float xn1 = x1 * rms * g[lane];
        float xn2 = x2 * rms * g[lane + 64];
        base[lane]      = (_Float16)(xn1 * c - xn2 * sn);
        base[lane + 64] = (_Float16)(xn2 * c + xn1 * sn);
    }
}

// ---------------------------------------------------------------------------
// GQA-shared flash attention, fp16 MFMA (verified round 5).
// ---------------------------------------------------------------------------
#define FAM 32     // q rows per wave
#define FAN 64     // kv tile rows
#define LQK 136    // Ks row stride (halves)
#define LVP 68     // Vt/Ps row stride (halves)

__global__ __launch_bounds__(256, 2) void flash_attn_gqa(
        const _Float16* __restrict__ qkv, _Float16* __restrict__ attn) {
    __shared__ __align__(16) _Float16 Ks[FAN][LQK];
    __shared__ __align__(16) _Float16 Vt[HD][LVP];
    __shared__ __align__(16) _Float16 Ps[4][FAM][LVP];

    const int tid = threadIdx.x;
    const int wave = tid >> 6, lane = tid & 63;
    const int fl = lane & 15, quad = lane >> 4;

    const int bd = blockIdx.x;
    const int c = bd & 255, sflip = bd >> 8;
    const int qt = sflip ? 63 - (c & 63) : (c & 63);
    const int kvh = (sflip << 2) + (c >> 6);
    const int h = kvh * 4 + wave;
    const int m0 = qt * FAM;
    const float scale = 0.08838834764831845f;  // HD^-0.5

    half8 qf[2][4];
    #pragma unroll
    for (int mt = 0; mt < 2; ++mt)
        #pragma unroll
        for (int ks = 0; ks < 4; ++ks)
            qf[mt][ks] = *(const half8*)(qkv
                + (size_t)(m0 + mt * 16 + fl) * QKV_DIM + h * HD + ks * 32 + quad * 8);

    float m_prev[2][4], l_prev[2][4];
    #pragma unroll
    for (int mt = 0; mt < 2; ++mt)
        #pragma unroll
        for (int r = 0; r < 4; ++r) { m_prev[mt][r] = -1e30f; l_prev[mt][r] = 0.f; }
    floatx4 oacc[2][8] = {};

    const int tmax = (m0 + FAM - 1) / FAN;
    for (int t = 0; t <= tmax; ++t) {
        const int n0 = t * FAN;
        __syncthreads();   // (A) all waves done reading prev Ks/Vt

        #pragma unroll
        for (int l = 0; l < 4; ++l) {
            const int f = tid + l * 256;
            const int r = f >> 4, c8 = (f & 15) * 8;
            *(half8*)&Ks[r][c8] = *(const half8*)(qkv
                + (size_t)(n0 + r) * QKV_DIM + K_OFF + kvh * HD + c8);
        }
        {
            const int p = tid & 31, g0 = tid >> 5;
            #pragma unroll
            for (int gi = 0; gi < 2; ++gi) {
                const int g = g0 + gi * 8;
                const _Float16* v0p = qkv + (size_t)(n0 + 2 * p) * QKV_DIM
                                      + V_OFF + kvh * HD + 8 * g;
                half8 va = *(const half8*)v0p;
                half8 vb = *(const half8*)(v0p + QKV_DIM);
                #pragma unroll
                for (int i = 0; i < 8; ++i) {
                    half2v hh; hh[0] = va[i]; hh[1] = vb[i];
                    *(half2v*)&Vt[8 * g + i][2 * p] = hh;
                }
            }
        }
        __syncthreads();   // (B) tiles staged

        floatx4 sacc[2][4] = {};
        __builtin_amdgcn_s_setprio(1);
        #pragma unroll
        for (int ks = 0; ks < 4; ++ks)
            #pragma unroll
            for (int nt = 0; nt < 4; ++nt) {
                half8 bf = *(const half8*)&Ks[nt * 16 + fl][ks * 32 + quad * 8];
                sacc[0][nt] = __builtin_amdgcn_mfma_f32_16x16x32_f16(
                    qf[0][ks], bf, sacc[0][nt], 0, 0, 0);
                sacc[1][nt] = __builtin_amdgcn_mfma_f32_16x16x32_f16(
                    qf[1][ks], bf, sacc[1][nt], 0, 0, 0);
            }
        __builtin_amdgcn_s_setprio(0);

        const bool diag = (t == tmax);
        float mx[2][4];
        #pragma unroll
        for (int mt = 0; mt < 2; ++mt)
            #pragma unroll
            for (int r = 0; r < 4; ++r) mx[mt][r] = -1e30f;
        #pragma unroll
        for (int mt = 0; mt < 2; ++mt)
            #pragma unroll
            for (int nt = 0; nt < 4; ++nt)
                #pragma unroll
                for (int r = 0; r < 4; ++r) {
                    float sv = sacc[mt][nt][r] * scale;
                    if (diag && (n0 + nt * 16 + fl > m0 + mt * 16 + quad * 4 + r))
                        sv = -1e30f;
                    sacc[mt][nt][r] = sv;
                    mx[mt][r] = fmaxf(mx[mt][r], sv);
                }
        #pragma unroll
        for (int mt = 0; mt < 2; ++mt)
            #pragma unroll
            for (int r = 0; r < 4; ++r)
                #pragma unroll
                for (int o = 8; o; o >>= 1)
                    mx[mt][r] = fmaxf(mx[mt][r], __shfl_xor(mx[mt][r], o));

        float alpha[2][4], rs[2][4];
        #pragma unroll
        for (int mt = 0; mt < 2; ++mt)
            #pragma unroll
            for (int r = 0; r < 4; ++r) {
                float nm = fmaxf(m_prev[mt][r], mx[mt][r]);
                alpha[mt][r] = __expf(m_prev[mt][r] - nm);
                m_prev[mt][r] = nm;
                rs[mt][r] = 0.f;
            }
        #pragma unroll
        for (int mt = 0; mt < 2; ++mt)
            #pragma unroll
            for (int nt = 0; nt < 4; ++nt)
                #pragma unroll
                for (int r = 0; r < 4; ++r) {
                    float p = __expf(sacc[mt][nt][r] - m_prev[mt][r]);
                    rs[mt][r] += p;
                    Ps[wave][mt * 16 + quad * 4 + r][nt * 16 + fl] = (_Float16)p;
                }
        #pragma unroll
        for (int mt = 0; mt < 2; ++mt)
            #pragma unroll
            for (int r = 0; r < 4; ++r) {
                #pragma unroll
                for (int o = 8; o; o >>= 1) rs[mt][r] += __shfl_xor(rs[mt][r], o);
                l_prev[mt][r] = l_prev[mt][r] * alpha[mt][r] + rs[mt][r];
            }
        #pragma unroll
        for (int mt = 0; mt < 2; ++mt)
            #pragma unroll
            for (int dt = 0; dt < 8; ++dt)
                #pragma unroll
                for (int r = 0; r < 4; ++r) oacc[mt][dt][r] *= alpha[mt][r];

        __builtin_amdgcn_s_setprio(1);
        #pragma unroll
        for (int ks2 = 0; ks2 < 2; ++ks2) {
            half8 pa[2];
            #pragma unroll
            for (int mt = 0; mt < 2; ++mt) {
                half4v plo = *(const half4v*)&Ps[wave][mt * 16 + fl][ks2 * 32 + quad * 8];
                half4v phi = *(const half4v*)&Ps[wave][mt * 16 + fl][ks2 * 32 + quad * 8 + 4];
                pa[mt] = __builtin_shufflevector(plo, phi, 0, 1, 2, 3, 4, 5, 6, 7);
            }
            #pragma unroll
            for (int dt = 0; dt < 8; ++dt) {
                half4v vlo = *(const half4v*)&Vt[dt * 16 + fl][ks2 * 32 + quad * 8];
                half4v vhi = *(const half4v*)&Vt[dt * 16 + fl][ks2 * 32 + quad * 8 + 4];
                half8 vb = __builtin_shufflevector(vlo, vhi, 0, 1, 2, 3, 4, 5, 6, 7);
                oacc[0][dt] = __builtin_amdgcn_mfma_f32_16x16x32_f16(
                    pa[0], vb, oacc[0][dt], 0, 0, 0);
                oacc[1][dt] = __builtin_amdgcn_mfma_f32_16x16x32_f16(
                    pa[1], vb, oacc[1][dt], 0, 0, 0);
            }
        }
        __builtin_amdgcn_s_setprio(0);
    }

    #pragma unroll
    for (int mt = 0; mt < 2; ++mt) {
        float linv[4];
        #pragma unroll
        for (int r = 0; r < 4; ++r) linv[r] = 1.0f / l_prev[mt][r];
        #pragma unroll
        for (int dt = 0; dt < 8; ++dt)
            #pragma unroll
            for (int r = 0; r < 4; ++r)
                attn[(size_t)(m0 + mt * 16 + quad * 4 + r) * NQHD
                     + h * HD + dt * 16 + fl] = (_Float16)(oacc[mt][dt][r] * linv[r]);
    }
}

// ---------------------------------------------------------------------------
extern "C" void kernel_launch(void* const* d_in, const int* in_sizes, int n_in,
                              void* d_out, int out_size, void* d_ws, size_t ws_size,
                              hipStream_t stream) {
    // inputs: positions, hidden_states, Wqkv, Wo, q_gamma, k_gamma, cos, sin
    const float* hidden = (const float*)d_in[1];
    const float* Wqkv   = (const float*)d_in[2];
    const float* Wo     = (const float*)d_in[3];
    const float* qg     = (const float*)d_in[4];
    const float* kg     = (const float*)d_in[5];
    const float* cosb   = (const float*)d_in[6];
    const float* sinb   = (const float*)d_in[7];
    float* out = (float*)d_out;

    // ws layout (67.1 MB total):
    //   buf0: h16 [2048][4096]     -> later attn16 [2048][4096] (same size)
    //   buf1: wT  [6144][4096]     -> later woT [4096][4096] (smaller)
    // qkv16 [2048][6144] fp16 lives in d_out; dead before gemm2 overwrites it.
    _Float16* buf0  = (_Float16*)d_ws;
    _Float16* wT    = buf0 + (size_t)S_LEN * HIDDEN;
    _Float16* qkv16 = (_Float16*)d_out;
    _Float16* attn16 = buf0;

    // 1) convert hidden -> fp16
    conv_f32_f16<<<(S_LEN * HIDDEN) / 2048, 256, 0, stream>>>(hidden, buf0);
    // 2) Wqkv [K=4096][N=6144] -> wT [6144][4096] fp16
    conv_w_transpose<<<dim3(QKV_DIM / 64, HIDDEN / 64), 256, 0, stream>>>(
        Wqkv, wT, QKV_DIM, HIDDEN);
    // 3) qkv16 = h16 @ wT^T  (128x128 tiles, 48x16 = 768 blocks)
    gemm_bt_db<_Float16><<<dim3(QKV_DIM / 128, S_LEN / 128), 256, 0, stream>>>(
        buf0, wT, qkv16, HIDDEN, QKV_DIM);
    // 4) RMSNorm + RoPE in place (fp16), wave-per-head
    rmsnorm_rope_w<<<S_LEN, 256, 0, stream>>>(qkv16, qg, kg, cosb, sinb);
    // 5) GQA-shared flash attention -> attn16 (buf0; h16 dead)
    flash_attn_gqa<<<dim3((S_LEN / FAM) * NKV), 256, 0, stream>>>(qkv16, attn16);
    // 6) Wo [4096][4096] -> woT fp16 (reuses wT slot; Wqkv16 dead)
    conv_w_transpose<<<dim3(HIDDEN / 64, NQHD / 64), 256, 0, stream>>>(
        Wo, wT, HIDDEN, NQHD);
    // 7) out = attn16 @ woT^T  (128x128 tiles, 32x16 = 512 blocks)
    gemm_bt_db<float><<<dim3(HIDDEN / 128, S_LEN / 128), 256, 0, stream>>>(
        attn16, wT, out, NQHD, HIDDEN);
}

// Round 6
// 547.516 us; speedup vs baseline: 1.1963x; 1.0487x over previous
//
#include <hip/hip_runtime.h>
#include <hip/hip_bf16.h>

// Qwen3 attention block. Round 9: faithful m201 8-phase GEMM port.
//   - gemm_8ph<CT,BN>: 256xBN tile, BK=64, 8 waves (2Mx4N), dbuf LDS with
//     ROW-half split (128B rows -> rounds 6/8's verified zero-conflict
//     swizzle preserved). 4 phases/K-tile (2 for BN=128), each
//     {ds_read subtile | 1 half-stage prefetch | barrier | lgkmcnt(0)+
//     sched_barrier | setprio(1) 16 MFMA setprio(0) | barrier}.
//     Counted vmcnt once per K-tile at entry (4 / 2, never 0); stage
//     placement proven against read-completion barriers.
//   - QKV: 256x256 (192 blocks); Wo: 256x128 (256 blocks, full fill).
// rmsnorm_rope_w / flash / convs unchanged (verified rounds 5/8).
// B=1, S=2048, HIDDEN=4096, NQ=32, NKV=8 (GQA R=4), HD=128.

#define S_LEN   2048
#define HIDDEN  4096
#define NQ      32
#define NKV     8
#define HD      128
#define QKV_DIM 6144      // (NQ + 2*NKV) * HD
#define NQHD    4096      // NQ * HD
#define K_OFF   4096
#define V_OFF   5120
#define EPSF    1e-6f

typedef _Float16 half8 __attribute__((ext_vector_type(8)));
typedef _Float16 half4v __attribute__((ext_vector_type(4)));
typedef _Float16 half2v __attribute__((ext_vector_type(2)));
typedef float floatx4 __attribute__((ext_vector_type(4)));

__device__ __forceinline__ void gload_lds16(const void* g, void* l) {
    __builtin_amdgcn_global_load_lds(
        (const __attribute__((address_space(1))) unsigned int*)g,
        (__attribute__((address_space(3))) unsigned int*)l, 16, 0, 0);
}

// ---------------------------------------------------------------------------
// fp32 -> fp16 elementwise convert (8 elems/thread)
// ---------------------------------------------------------------------------
__global__ __launch_bounds__(256) void conv_f32_f16(const float* __restrict__ src,
                                                    _Float16* __restrict__ dst) {
    const size_t i = ((size_t)blockIdx.x * 256 + threadIdx.x) * 8;
    float4 a = *(const float4*)(src + i);
    float4 b = *(const float4*)(src + i + 4);
    half8 h;
    h[0] = (_Float16)a.x; h[1] = (_Float16)a.y; h[2] = (_Float16)a.z; h[3] = (_Float16)a.w;
    h[4] = (_Float16)b.x; h[5] = (_Float16)b.y; h[6] = (_Float16)b.z; h[7] = (_Float16)b.w;
    *(half8*)(dst + i) = h;
}

// ---------------------------------------------------------------------------
// W[K][N] fp32 -> Wt[N][K] fp16 (transpose + convert), 64x64 tiles via LDS.
// ---------------------------------------------------------------------------
__global__ __launch_bounds__(256) void conv_w_transpose(const float* __restrict__ src,
                                                        _Float16* __restrict__ dst,
                                                        int N, int K) {
    __shared__ float T[64][65];
    const int tid = threadIdx.x;
    const int n0 = blockIdx.x * 64, k0 = blockIdx.y * 64;
    const int rr = tid >> 4, cc = (tid & 15) * 4;
    #pragma unroll
    for (int l = 0; l < 4; ++l) {
        const int r = rr + l * 16;
        *(float4*)&T[r][cc] = *(const float4*)(src + (size_t)(k0 + r) * N + n0 + cc);
    }
    __syncthreads();
    #pragma unroll
    for (int l = 0; l < 4; ++l) {
        const int rn = rr + l * 16;
        half4v h;
        h[0] = (_Float16)T[cc + 0][rn];
        h[1] = (_Float16)T[cc + 1][rn];
        h[2] = (_Float16)T[cc + 2][rn];
        h[3] = (_Float16)T[cc + 3][rn];
        *(half4v*)(dst + (size_t)(n0 + rn) * K + k0 + cc) = h;
    }
}

// ---------------------------------------------------------------------------
// 8-phase GEMM: C[M][ldc] = A[M][K] @ Bt[N][K]^T, fp16 in, CT out.
// BM=256 x BN tile, BK=64, 512 thr = 8 waves (2Mx4N). A stored as two
// ROW-halves (128 rows x 64 halves, 128B rows); B likewise (BN=256) or one
// region (BN=128). Swizzle identical to rounds 6/8 (measured 0 conflicts):
// LDS[r][c] = G[r][c ^ (r&7)] in 16B chunks; reads use chunk quad^(fl&7).
// ---------------------------------------------------------------------------
#define MFMA_PH(MB, NB)                                                        \
    asm volatile("s_waitcnt lgkmcnt(0)" ::: "memory");                         \
    __builtin_amdgcn_sched_barrier(0);                                         \
    __builtin_amdgcn_s_setprio(1);                                             \
    _Pragma("unroll")                                                          \
    for (int ks = 0; ks < 2; ++ks)                                             \
        _Pragma("unroll")                                                      \
        for (int mt = 0; mt < 4; ++mt)                                         \
            _Pragma("unroll")                                                  \
            for (int nt = 0; nt < 2; ++nt)                                     \
                acc[(MB) + mt][(NB) + nt] =                                    \
                    __builtin_amdgcn_mfma_f32_16x16x32_f16(                    \
                        af[mt][ks], bf[(NB) + nt][ks],                         \
                        acc[(MB) + mt][(NB) + nt], 0, 0, 0);                   \
    __builtin_amdgcn_s_setprio(0);                                             \
    __builtin_amdgcn_sched_barrier(0);

#define READ_AF(H)                                                             \
    _Pragma("unroll")                                                          \
    for (int mt = 0; mt < 4; ++mt) {                                           \
        const char* p_ = aB + ((H) * 64 + mt * 16 + fl) * 128;                 \
        af[mt][0] = *(const half8*)(p_ + cs0);                                 \
        af[mt][1] = *(const half8*)(p_ + cs1);                                 \
    }

#define READ_BF(NB)                                                            \
    _Pragma("unroll")                                                          \
    for (int j = 0; j < 2; ++j) {                                              \
        const char* p_ = bB + (((NB) + j) * 16 + fl) * 128;                    \
        bf[(NB) + j][0] = *(const half8*)(p_ + cs0);                           \
        bf[(NB) + j][1] = *(const half8*)(p_ + cs1);                           \
    }

#define PHBAR asm volatile("s_barrier" ::: "memory")

template <typename CT, int BN>
__global__ __launch_bounds__(512, 2) void gemm_8ph(const _Float16* __restrict__ A,
                                                   const _Float16* __restrict__ Bt,
                                                   CT* __restrict__ C,
                                                   int K, int ldc) {
    constexpr int NI = BN / 64;            // n-frags per wave (4 or 2)
    constexpr int NBH = BN / 128;          // stored B halves (2 or 1)

    __shared__ _Float16 sA[2][2][128 * 64];      // 64 KiB
    __shared__ _Float16 sB[2][NBH][128 * 64];    // 64 or 32 KiB

    const int tid = threadIdx.x;
    const int wave = tid >> 6, lane = tid & 63;
    const int fl = lane & 15, quad = lane >> 4;
    const int wmh = wave >> 2;                   // A stored-half index
    const int wn  = (wave & 3) * (BN / 4);

    const int m0 = blockIdx.y * 256, n0 = blockIdx.x * BN;

    // staging: per gload_lds a wave covers 8 rows x 8 chunks of 16B; source
    // chunk pre-swizzled (rule #21) so LDS stays linear.
    const int srow = lane >> 3;
    const int sch  = ((lane & 7) ^ srow) * 8;    // halves

    auto stA = [&](int buf, int kt, int h) {
        const _Float16* s = A + (size_t)(m0 + h * 128 + wave * 8 + srow) * K
                            + kt * 64 + sch;
        _Float16* d = &sA[buf][h][(wave * 8) * 64];
        gload_lds16(s, d);
        gload_lds16(s + (size_t)64 * K, d + 64 * 64);
    };
    auto stB = [&](int buf, int kt, int h) {
        const _Float16* s = Bt + (size_t)(n0 + h * 128 + wave * 8 + srow) * K
                            + kt * 64 + sch;
        _Float16* d = &sB[buf][h][(wave * 8) * 64];
        gload_lds16(s, d);
        gload_lds16(s + (size_t)64 * K, d + 64 * 64);
    };

    floatx4 acc[8][NI] = {};
    const int cs0 = (quad ^ (fl & 7)) << 4;
    const int cs1 = ((4 + quad) ^ (fl & 7)) << 4;

    // prologue: tile-0 fully + tile-1's B halves (A1 staged in-loop at t=0).
    // vmcnt(VN) at tile entry leaves exactly next-tile B-stages outstanding.
    if constexpr (BN == 256) {
        stA(0, 0, 0); stA(0, 0, 1);
        stB(0, 0, 0); stB(0, 0, 1);
        stB(1, 1, 0); stB(1, 1, 1);
    } else {
        stA(0, 0, 0); stA(0, 0, 1);
        stB(0, 0, 0);
        stB(1, 1, 0);
    }

    const int NT = K >> 6;
    for (int t = 0; t < NT; ++t) {
        const int cur = t & 1;
        const char* aB = (const char*)&sA[cur][wmh][0];
        const char* bB = (BN == 256)
            ? (const char*)&sB[cur][wn >> 7][0] + (size_t)(wn & 64) * 128
            : (const char*)&sB[cur][0][0] + (size_t)wn * 128;

        half8 af[4][2], bf[NI][2];

        // tile entry: tile-t data landed (counted; never drains prefetch)
        if constexpr (BN == 256)
            asm volatile("s_waitcnt vmcnt(4)\n\ts_barrier" ::: "memory");
        else
            asm volatile("s_waitcnt vmcnt(2)\n\ts_barrier" ::: "memory");

        if constexpr (BN == 256) {
            // ---- ph0: (Mlo, Nlo); stage A-lo(t+1) ----
            READ_AF(0)
            READ_BF(0)
            if (t + 1 < NT) stA(cur ^ 1, t + 1, 0);
            PHBAR;
            MFMA_PH(0, 0)
            PHBAR;
            // ---- ph1: (Mlo, Nhi); stage A-hi(t+1) ----
            READ_BF(2)
            if (t + 1 < NT) stA(cur ^ 1, t + 1, 1);
            PHBAR;
            MFMA_PH(0, 2)
            PHBAR;
            // ---- ph2: (Mhi, Nlo); stage B-lo(t+2) (B reads done after ph1) ----
            READ_AF(1)
            if (t + 2 < NT) stB(cur, t + 2, 0);
            PHBAR;
            MFMA_PH(4, 0)
            PHBAR;
            // ---- ph3: (Mhi, Nhi); stage B-hi(t+2) ----
            if (t + 2 < NT) stB(cur, t + 2, 1);
            PHBAR;
            MFMA_PH(4, 2)
            // ph3 exit barrier == next tile's entry barrier (loop top)
        } else {
            // ---- ph0: (Mlo, all N); stage A-lo(t+1) ----
            READ_AF(0)
            READ_BF(0)
            if (t + 1 < NT) stA(cur ^ 1, t + 1, 0);
            PHBAR;
            MFMA_PH(0, 0)
            PHBAR;
            // ---- ph1: (Mhi, all N); stage A-hi(t+1) + B(t+2) ----
            READ_AF(1)
            if (t + 1 < NT) stA(cur ^ 1, t + 1, 1);
            if (t + 2 < NT) stB(cur, t + 2, 0);
            PHBAR;
            MFMA_PH(4, 0)
            // ph1 exit barrier == next tile's entry barrier (loop top)
        }
    }

    #pragma unroll
    for (int mi = 0; mi < 8; ++mi)
        #pragma unroll
        for (int ni = 0; ni < NI; ++ni)
            #pragma unroll
            for (int r = 0; r < 4; ++r)
                C[(size_t)(m0 + wmh * 128 + mi * 16 + quad * 4 + r) * ldc
                  + n0 + wn + ni * 16 + fl] = (CT)acc[mi][ni][r];
}

#undef MFMA_PH
#undef READ_AF
#undef READ_BF
#undef PHBAR

// ---------------------------------------------------------------------------
// Fused RMSNorm + RoPE, wave-per-head (verified round 8).
// ---------------------------------------------------------------------------
__global__ __launch_bounds__(256) void rmsnorm_rope_w(_Float16* __restrict__ qkv,
                                                      const float* __restrict__ qg,
                                                      const float* __restrict__ kg,
                                                      const float* __restrict__ cosb,
                                                      const float* __restrict__ sinb) {
    const int s = blockIdx.x;
    const int wave = threadIdx.x >> 6, lane = threadIdx.x & 63;
    const float c  = cosb[s * 64 + lane];
    const float sn = sinb[s * 64 + lane];

    #pragma unroll
    for (int hi = 0; hi < 10; ++hi) {
        const int h = hi * 4 + wave;   // 0..39
        const bool isq = (h < NQ);
        _Float16* base = qkv + (size_t)s * QKV_DIM
                         + (isq ? h * HD : K_OFF + (h - NQ) * HD);
        float x1 = (float)base[lane];
        float x2 = (float)base[lane + 64];
        float ss = x1 * x1 + x2 * x2;
        #pragma unroll
        for (int o = 32; o; o >>= 1) ss += __shfl_xor(ss, o);
        float rms = rsqrtf(ss * (1.0f / (float)HD) + EPSF);
        const float* g = isq ? qg : kg;
        float xn1 = x1 * rms * g[lane];
        float xn2 = x2 * rms * g[lane + 64];
        base[lane]      = (_Float16)(xn1 * c - xn2 * sn);
        base[lane + 64] = (_Float16)(xn2 * c + xn1 * sn);
    }
}

// ---------------------------------------------------------------------------
// GQA-shared flash attention, fp16 MFMA (verified round 5).
// ---------------------------------------------------------------------------
#define FAM 32     // q rows per wave
#define FAN 64     // kv tile rows
#define LQK 136    // Ks row stride (halves)
#define LVP 68     // Vt/Ps row stride (halves)

__global__ __launch_bounds__(256, 2) void flash_attn_gqa(
        const _Float16* __restrict__ qkv, _Float16* __restrict__ attn) {
    __shared__ __align__(16) _Float16 Ks[FAN][LQK];
    __shared__ __align__(16) _Float16 Vt[HD][LVP];
    __shared__ __align__(16) _Float16 Ps[4][FAM][LVP];

    const int tid = threadIdx.x;
    const int wave = tid >> 6, lane = tid & 63;
    const int fl = lane & 15, quad = lane >> 4;

    const int bd = blockIdx.x;
    const int c = bd & 255, sflip = bd >> 8;
    const int qt = sflip ? 63 - (c & 63) : (c & 63);
    const int kvh = (sflip << 2) + (c >> 6);
    const int h = kvh * 4 + wave;
    const int m0 = qt * FAM;
    const float scale = 0.08838834764831845f;  // HD^-0.5

    half8 qf[2][4];
    #pragma unroll
    for (int mt = 0; mt < 2; ++mt)
        #pragma unroll
        for (int ks = 0; ks < 4; ++ks)
            qf[mt][ks] = *(const half8*)(qkv
                + (size_t)(m0 + mt * 16 + fl) * QKV_DIM + h * HD + ks * 32 + quad * 8);

    float m_prev[2][4], l_prev[2][4];
    #pragma unroll
    for (int mt = 0; mt < 2; ++mt)
        #pragma unroll
        for (int r = 0; r < 4; ++r) { m_prev[mt][r] = -1e30f; l_prev[mt][r] = 0.f; }
    floatx4 oacc[2][8] = {};

    const int tmax = (m0 + FAM - 1) / FAN;
    for (int t = 0; t <= tmax; ++t) {
        const int n0 = t * FAN;
        __syncthreads();   // (A) all waves done reading prev Ks/Vt

        #pragma unroll
        for (int l = 0; l < 4; ++l) {
            const int f = tid + l * 256;
            const int r = f >> 4, c8 = (f & 15) * 8;
            *(half8*)&Ks[r][c8] = *(const half8*)(qkv
                + (size_t)(n0 + r) * QKV_DIM + K_OFF + kvh * HD + c8);
        }
        {
            const int p = tid & 31, g0 = tid >> 5;
            #pragma unroll
            for (int gi = 0; gi < 2; ++gi) {
                const int g = g0 + gi * 8;
                const _Float16* v0p = qkv + (size_t)(n0 + 2 * p) * QKV_DIM
                                      + V_OFF + kvh * HD + 8 * g;
                half8 va = *(const half8*)v0p;
                half8 vb = *(const half8*)(v0p + QKV_DIM);
                #pragma unroll
                for (int i = 0; i < 8; ++i) {
                    half2v hh; hh[0] = va[i]; hh[1] = vb[i];
                    *(half2v*)&Vt[8 * g + i][2 * p] = hh;
                }
            }
        }
        __syncthreads();   // (B) tiles staged

        floatx4 sacc[2][4] = {};
        __builtin_amdgcn_s_setprio(1);
        #pragma unroll
        for (int ks = 0; ks < 4; ++ks)
            #pragma unroll
            for (int nt = 0; nt < 4; ++nt) {
                half8 bf = *(const half8*)&Ks[nt * 16 + fl][ks * 32 + quad * 8];
                sacc[0][nt] = __builtin_amdgcn_mfma_f32_16x16x32_f16(
                    qf[0][ks], bf, sacc[0][nt], 0, 0, 0);
                sacc[1][nt] = __builtin_amdgcn_mfma_f32_16x16x32_f16(
                    qf[1][ks], bf, sacc[1][nt], 0, 0, 0);
            }
        __builtin_amdgcn_s_setprio(0);

        const bool diag = (t == tmax);
        float mx[2][4];
        #pragma unroll
        for (int mt = 0; mt < 2; ++mt)
            #pragma unroll
            for (int r = 0; r < 4; ++r) mx[mt][r] = -1e30f;
        #pragma unroll
        for (int mt = 0; mt < 2; ++mt)
            #pragma unroll
            for (int nt = 0; nt < 4; ++nt)
                #pragma unroll
                for (int r = 0; r < 4; ++r) {
                    float sv = sacc[mt][nt][r] * scale;
                    if (diag && (n0 + nt * 16 + fl > m0 + mt * 16 + quad * 4 + r))
                        sv = -1e30f;
                    sacc[mt][nt][r] = sv;
                    mx[mt][r] = fmaxf(mx[mt][r], sv);
                }
        #pragma unroll
        for (int mt = 0; mt < 2; ++mt)
            #pragma unroll
            for (int r = 0; r < 4; ++r)
                #pragma unroll
                for (int o = 8; o; o >>= 1)
                    mx[mt][r] = fmaxf(mx[mt][r], __shfl_xor(mx[mt][r], o));

        float alpha[2][4], rs[2][4];
        #pragma unroll
        for (int mt = 0; mt < 2; ++mt)
            #pragma unroll
            for (int r = 0; r < 4; ++r) {
                float nm = fmaxf(m_prev[mt][r], mx[mt][r]);
                alpha[mt][r] = __expf(m_prev[mt][r] - nm);
                m_prev[mt][r] = nm;
                rs[mt][r] = 0.f;
            }
        #pragma unroll
        for (int mt = 0; mt < 2; ++mt)
            #pragma unroll
            for (int nt = 0; nt < 4; ++nt)
                #pragma unroll
                for (int r = 0; r < 4; ++r) {
                    float p = __expf(sacc[mt][nt][r] - m_prev[mt][r]);
                    rs[mt][r] += p;
                    Ps[wave][mt * 16 + quad * 4 + r][nt * 16 + fl] = (_Float16)p;
                }
        #pragma unroll
        for (int mt = 0; mt < 2; ++mt)
            #pragma unroll
            for (int r = 0; r < 4; ++r) {
                #pragma unroll
                for (int o = 8; o; o >>= 1) rs[mt][r] += __shfl_xor(rs[mt][r], o);
                l_prev[mt][r] = l_prev[mt][r] * alpha[mt][r] + rs[mt][r];
            }
        #pragma unroll
        for (int mt = 0; mt < 2; ++mt)
            #pragma unroll
            for (int dt = 0; dt < 8; ++dt)
                #pragma unroll
                for (int r = 0; r < 4; ++r) oacc[mt][dt][r] *= alpha[mt][r];

        __builtin_amdgcn_s_setprio(1);
        #pragma unroll
        for (int ks2 = 0; ks2 < 2; ++ks2) {
            half8 pa[2];
            #pragma unroll
            for (int mt = 0; mt < 2; ++mt) {
                half4v plo = *(const half4v*)&Ps[wave][mt * 16 + fl][ks2 * 32 + quad * 8];
                half4v phi = *(const half4v*)&Ps[wave][mt * 16 + fl][ks2 * 32 + quad * 8 + 4];
                pa[mt] = __builtin_shufflevector(plo, phi, 0, 1, 2, 3, 4, 5, 6, 7);
            }
            #pragma unroll
            for (int dt = 0; dt < 8; ++dt) {
                half4v vlo = *(const half4v*)&Vt[dt * 16 + fl][ks2 * 32 + quad * 8];
                half4v vhi = *(const half4v*)&Vt[dt * 16 + fl][ks2 * 32 + quad * 8 + 4];
                half8 vb = __builtin_shufflevector(vlo, vhi, 0, 1, 2, 3, 4, 5, 6, 7);
                oacc[0][dt] = __builtin_amdgcn_mfma_f32_16x16x32_f16(
                    pa[0], vb, oacc[0][dt], 0, 0, 0);
                oacc[1][dt] = __builtin_amdgcn_mfma_f32_16x16x32_f16(
                    pa[1], vb, oacc[1][dt], 0, 0, 0);
            }
        }
        __builtin_amdgcn_s_setprio(0);
    }

    #pragma unroll
    for (int mt = 0; mt < 2; ++mt) {
        float linv[4];
        #pragma unroll
        for (int r = 0; r < 4; ++r) linv[r] = 1.0f / l_prev[mt][r];
        #pragma unroll
        for (int dt = 0; dt < 8; ++dt)
            #pragma unroll
            for (int r = 0; r < 4; ++r)
                attn[(size_t)(m0 + mt * 16 + quad * 4 + r) * NQHD
                     + h * HD + dt * 16 + fl] = (_Float16)(oacc[mt][dt][r] * linv[r]);
    }
}

// ---------------------------------------------------------------------------
extern "C" void kernel_launch(void* const* d_in, const int* in_sizes, int n_in,
                              void* d_out, int out_size, void* d_ws, size_t ws_size,
                              hipStream_t stream) {
    // inputs: positions, hidden_states, Wqkv, Wo, q_gamma, k_gamma, cos, sin
    const float* hidden = (const float*)d_in[1];
    const float* Wqkv   = (const float*)d_in[2];
    const float* Wo     = (const float*)d_in[3];
    const float* qg     = (const float*)d_in[4];
    const float* kg     = (const float*)d_in[5];
    const float* cosb   = (const float*)d_in[6];
    const float* sinb   = (const float*)d_in[7];
    float* out = (float*)d_out;

    // ws layout (67.1 MB total):
    //   buf0: h16 [2048][4096]     -> later attn16 [2048][4096] (same size)
    //   buf1: wT  [6144][4096]     -> later woT [4096][4096] (smaller)
    // qkv16 [2048][6144] fp16 lives in d_out; dead before gemm2 overwrites it.
    _Float16* buf0  = (_Float16*)d_ws;
    _Float16* wT    = buf0 + (size_t)S_LEN * HIDDEN;
    _Float16* qkv16 = (_Float16*)d_out;
    _Float16* attn16 = buf0;

    // 1) convert hidden -> fp16
    conv_f32_f16<<<(S_LEN * HIDDEN) / 2048, 256, 0, stream>>>(hidden, buf0);
    // 2) Wqkv [K=4096][N=6144] -> wT [6144][4096] fp16
    conv_w_transpose<<<dim3(QKV_DIM / 64, HIDDEN / 64), 256, 0, stream>>>(
        Wqkv, wT, QKV_DIM, HIDDEN);
    // 3) qkv16 = h16 @ wT^T  (256x256 8-phase, 24x8 = 192 blocks)
    gemm_8ph<_Float16, 256><<<dim3(QKV_DIM / 256, S_LEN / 256), 512, 0, stream>>>(
        buf0, wT, qkv16, HIDDEN, QKV_DIM);
    // 4) RMSNorm + RoPE in place (fp16), wave-per-head
    rmsnorm_rope_w<<<S_LEN, 256, 0, stream>>>(qkv16, qg, kg, cosb, sinb);
    // 5) GQA-shared flash attention -> attn16 (buf0; h16 dead)
    flash_attn_gqa<<<dim3((S_LEN / FAM) * NKV), 256, 0, stream>>>(qkv16, attn16);
    // 6) Wo [4096][4096] -> woT fp16 (reuses wT slot; Wqkv16 dead)
    conv_w_transpose<<<dim3(HIDDEN / 64, NQHD / 64), 256, 0, stream>>>(
        Wo, wT, HIDDEN, NQHD);
    // 7) out = attn16 @ woT^T  (256x128 8-phase, 32x8 = 256 blocks, full fill)
    gemm_8ph<float, 128><<<dim3(HIDDEN / 128, S_LEN / 256), 512, 0, stream>>>(
        attn16, wT, out, NQHD, HIDDEN);
}

// Round 7
// 540.567 us; speedup vs baseline: 1.2117x; 1.0129x over previous
//
#include <hip/hip_runtime.h>
#include <hip/hip_bf16.h>

// Qwen3 attention block. Round 10: flash attention latency package.
//   - flash_attn_gqa8: 8 waves/block (512 thr), wave = (head, 16-row m-half)
//     -> 16 waves/CU (4/SIMD, was 2/SIMD): TLP to hide latency.
//   - T14 async-STAGE: K/V tile t+1 loaded global->regs right after barrier B,
//     in flight across QK^T/softmax/PV of tile t; regs->LDS after barrier A.
//   - T13 defer-max (skip rescale unless __any(mx - m > 8)) + exp2-domain
//     softmax (fold scale*log2e; exp2f == v_exp_f32 directly).
// GEMMs (8-phase, round 9) / convs / rmsnorm unchanged.
// B=1, S=2048, HIDDEN=4096, NQ=32, NKV=8 (GQA R=4), HD=128.

#define S_LEN   2048
#define HIDDEN  4096
#define NQ      32
#define NKV     8
#define HD      128
#define QKV_DIM 6144      // (NQ + 2*NKV) * HD
#define NQHD    4096      // NQ * HD
#define K_OFF   4096
#define V_OFF   5120
#define EPSF    1e-6f

typedef _Float16 half8 __attribute__((ext_vector_type(8)));
typedef _Float16 half4v __attribute__((ext_vector_type(4)));
typedef _Float16 half2v __attribute__((ext_vector_type(2)));
typedef float floatx4 __attribute__((ext_vector_type(4)));

__device__ __forceinline__ void gload_lds16(const void* g, void* l) {
    __builtin_amdgcn_global_load_lds(
        (const __attribute__((address_space(1))) unsigned int*)g,
        (__attribute__((address_space(3))) unsigned int*)l, 16, 0, 0);
}

// ---------------------------------------------------------------------------
// fp32 -> fp16 elementwise convert (8 elems/thread)
// ---------------------------------------------------------------------------
__global__ __launch_bounds__(256) void conv_f32_f16(const float* __restrict__ src,
                                                    _Float16* __restrict__ dst) {
    const size_t i = ((size_t)blockIdx.x * 256 + threadIdx.x) * 8;
    float4 a = *(const float4*)(src + i);
    float4 b = *(const float4*)(src + i + 4);
    half8 h;
    h[0] = (_Float16)a.x; h[1] = (_Float16)a.y; h[2] = (_Float16)a.z; h[3] = (_Float16)a.w;
    h[4] = (_Float16)b.x; h[5] = (_Float16)b.y; h[6] = (_Float16)b.z; h[7] = (_Float16)b.w;
    *(half8*)(dst + i) = h;
}

// ---------------------------------------------------------------------------
// W[K][N] fp32 -> Wt[N][K] fp16 (transpose + convert), 64x64 tiles via LDS.
// ---------------------------------------------------------------------------
__global__ __launch_bounds__(256) void conv_w_transpose(const float* __restrict__ src,
                                                        _Float16* __restrict__ dst,
                                                        int N, int K) {
    __shared__ float T[64][65];
    const int tid = threadIdx.x;
    const int n0 = blockIdx.x * 64, k0 = blockIdx.y * 64;
    const int rr = tid >> 4, cc = (tid & 15) * 4;
    #pragma unroll
    for (int l = 0; l < 4; ++l) {
        const int r = rr + l * 16;
        *(float4*)&T[r][cc] = *(const float4*)(src + (size_t)(k0 + r) * N + n0 + cc);
    }
    __syncthreads();
    #pragma unroll
    for (int l = 0; l < 4; ++l) {
        const int rn = rr + l * 16;
        half4v h;
        h[0] = (_Float16)T[cc + 0][rn];
        h[1] = (_Float16)T[cc + 1][rn];
        h[2] = (_Float16)T[cc + 2][rn];
        h[3] = (_Float16)T[cc + 3][rn];
        *(half4v*)(dst + (size_t)(n0 + rn) * K + k0 + cc) = h;
    }
}

// ---------------------------------------------------------------------------
// 8-phase GEMM (verified round 9): C[M][ldc] = A[M][K] @ Bt[N][K]^T.
// ---------------------------------------------------------------------------
#define MFMA_PH(MB, NB)                                                        \
    asm volatile("s_waitcnt lgkmcnt(0)" ::: "memory");                         \
    __builtin_amdgcn_sched_barrier(0);                                         \
    __builtin_amdgcn_s_setprio(1);                                             \
    _Pragma("unroll")                                                          \
    for (int ks = 0; ks < 2; ++ks)                                             \
        _Pragma("unroll")                                                      \
        for (int mt = 0; mt < 4; ++mt)                                         \
            _Pragma("unroll")                                                  \
            for (int nt = 0; nt < 2; ++nt)                                     \
                acc[(MB) + mt][(NB) + nt] =                                    \
                    __builtin_amdgcn_mfma_f32_16x16x32_f16(                    \
                        af[mt][ks], bf[(NB) + nt][ks],                         \
                        acc[(MB) + mt][(NB) + nt], 0, 0, 0);                   \
    __builtin_amdgcn_s_setprio(0);                                             \
    __builtin_amdgcn_sched_barrier(0);

#define READ_AF(H)                                                             \
    _Pragma("unroll")                                                          \
    for (int mt = 0; mt < 4; ++mt) {                                           \
        const char* p_ = aB + ((H) * 64 + mt * 16 + fl) * 128;                 \
        af[mt][0] = *(const half8*)(p_ + cs0);                                 \
        af[mt][1] = *(const half8*)(p_ + cs1);                                 \
    }

#define READ_BF(NB)                                                            \
    _Pragma("unroll")                                                          \
    for (int j = 0; j < 2; ++j) {                                              \
        const char* p_ = bB + (((NB) + j) * 16 + fl) * 128;                    \
        bf[(NB) + j][0] = *(const half8*)(p_ + cs0);                           \
        bf[(NB) + j][1] = *(const half8*)(p_ + cs1);                           \
    }

#define PHBAR asm volatile("s_barrier" ::: "memory")

template <typename CT, int BN>
__global__ __launch_bounds__(512, 2) void gemm_8ph(const _Float16* __restrict__ A,
                                                   const _Float16* __restrict__ Bt,
                                                   CT* __restrict__ C,
                                                   int K, int ldc) {
    constexpr int NI = BN / 64;
    constexpr int NBH = BN / 128;

    __shared__ _Float16 sA[2][2][128 * 64];
    __shared__ _Float16 sB[2][NBH][128 * 64];

    const int tid = threadIdx.x;
    const int wave = tid >> 6, lane = tid & 63;
    const int fl = lane & 15, quad = lane >> 4;
    const int wmh = wave >> 2;
    const int wn  = (wave & 3) * (BN / 4);

    const int m0 = blockIdx.y * 256, n0 = blockIdx.x * BN;

    const int srow = lane >> 3;
    const int sch  = ((lane & 7) ^ srow) * 8;

    auto stA = [&](int buf, int kt, int h) {
        const _Float16* s = A + (size_t)(m0 + h * 128 + wave * 8 + srow) * K
                            + kt * 64 + sch;
        _Float16* d = &sA[buf][h][(wave * 8) * 64];
        gload_lds16(s, d);
        gload_lds16(s + (size_t)64 * K, d + 64 * 64);
    };
    auto stB = [&](int buf, int kt, int h) {
        const _Float16* s = Bt + (size_t)(n0 + h * 128 + wave * 8 + srow) * K
                            + kt * 64 + sch;
        _Float16* d = &sB[buf][h][(wave * 8) * 64];
        gload_lds16(s, d);
        gload_lds16(s + (size_t)64 * K, d + 64 * 64);
    };

    floatx4 acc[8][NI] = {};
    const int cs0 = (quad ^ (fl & 7)) << 4;
    const int cs1 = ((4 + quad) ^ (fl & 7)) << 4;

    if constexpr (BN == 256) {
        stA(0, 0, 0); stA(0, 0, 1);
        stB(0, 0, 0); stB(0, 0, 1);
        stB(1, 1, 0); stB(1, 1, 1);
    } else {
        stA(0, 0, 0); stA(0, 0, 1);
        stB(0, 0, 0);
        stB(1, 1, 0);
    }

    const int NT = K >> 6;
    for (int t = 0; t < NT; ++t) {
        const int cur = t & 1;
        const char* aB = (const char*)&sA[cur][wmh][0];
        const char* bB = (BN == 256)
            ? (const char*)&sB[cur][wn >> 7][0] + (size_t)(wn & 64) * 128
            : (const char*)&sB[cur][0][0] + (size_t)wn * 128;

        half8 af[4][2], bf[NI][2];

        if constexpr (BN == 256)
            asm volatile("s_waitcnt vmcnt(4)\n\ts_barrier" ::: "memory");
        else
            asm volatile("s_waitcnt vmcnt(2)\n\ts_barrier" ::: "memory");

        if constexpr (BN == 256) {
            READ_AF(0)
            READ_BF(0)
            if (t + 1 < NT) stA(cur ^ 1, t + 1, 0);
            PHBAR;
            MFMA_PH(0, 0)
            PHBAR;
            READ_BF(2)
            if (t + 1 < NT) stA(cur ^ 1, t + 1, 1);
            PHBAR;
            MFMA_PH(0, 2)
            PHBAR;
            READ_AF(1)
            if (t + 2 < NT) stB(cur, t + 2, 0);
            PHBAR;
            MFMA_PH(4, 0)
            PHBAR;
            if (t + 2 < NT) stB(cur, t + 2, 1);
            PHBAR;
            MFMA_PH(4, 2)
        } else {
            READ_AF(0)
            READ_BF(0)
            if (t + 1 < NT) stA(cur ^ 1, t + 1, 0);
            PHBAR;
            MFMA_PH(0, 0)
            PHBAR;
            READ_AF(1)
            if (t + 1 < NT) stA(cur ^ 1, t + 1, 1);
            if (t + 2 < NT) stB(cur, t + 2, 0);
            PHBAR;
            MFMA_PH(4, 0)
        }
    }

    #pragma unroll
    for (int mi = 0; mi < 8; ++mi)
        #pragma unroll
        for (int ni = 0; ni < NI; ++ni)
            #pragma unroll
            for (int r = 0; r < 4; ++r)
                C[(size_t)(m0 + wmh * 128 + mi * 16 + quad * 4 + r) * ldc
                  + n0 + wn + ni * 16 + fl] = (CT)acc[mi][ni][r];
}

#undef MFMA_PH
#undef READ_AF
#undef READ_BF
#undef PHBAR

// ---------------------------------------------------------------------------
// Fused RMSNorm + RoPE, wave-per-head (verified round 8).
// ---------------------------------------------------------------------------
__global__ __launch_bounds__(256) void rmsnorm_rope_w(_Float16* __restrict__ qkv,
                                                      const float* __restrict__ qg,
                                                      const float* __restrict__ kg,
                                                      const float* __restrict__ cosb,
                                                      const float* __restrict__ sinb) {
    const int s = blockIdx.x;
    const int wave = threadIdx.x >> 6, lane = threadIdx.x & 63;
    const float c  = cosb[s * 64 + lane];
    const float sn = sinb[s * 64 + lane];

    #pragma unroll
    for (int hi = 0; hi < 10; ++hi) {
        const int h = hi * 4 + wave;   // 0..39
        const bool isq = (h < NQ);
        _Float16* base = qkv + (size_t)s * QKV_DIM
                         + (isq ? h * HD : K_OFF + (h - NQ) * HD);
        float x1 = (float)base[lane];
        float x2 = (float)base[lane + 64];
        float ss = x1 * x1 + x2 * x2;
        #pragma unroll
        for (int o = 32; o; o >>= 1) ss += __shfl_xor(ss, o);
        float rms = rsqrtf(ss * (1.0f / (float)HD) + EPSF);
        const float* g = isq ? qg : kg;
        float xn1 = x1 * rms * g[lane];
        float xn2 = x2 * rms * g[lane + 64];
        base[lane]      = (_Float16)(xn1 * c - xn2 * sn);
        base[lane + 64] = (_Float16)(xn2 * c + xn1 * sn);
    }
}

// ---------------------------------------------------------------------------
// GQA-shared flash attention, 8 waves (512 thr). Wave = (head hw, m-half mt):
// 16 q-rows per wave. K/V staged once per tile for all 8 waves via T14
// async-split: tile t+1 global->regs issued after barrier B (in flight over
// compute of tile t), regs->LDS after barrier A. Softmax in exp2 domain with
// T13 defer-max. Balanced qt pairing as before.
// ---------------------------------------------------------------------------
#define FAM 32     // q rows per block
#define FAN 64     // kv tile rows
#define LQK 136    // Ks row stride (halves)
#define LVP 68     // Vt/Ps row stride (halves)
#define THR_L2 8.0f

__global__ __launch_bounds__(512, 4) void flash_attn_gqa8(
        const _Float16* __restrict__ qkv, _Float16* __restrict__ attn) {
    __shared__ __align__(16) _Float16 Ks[FAN][LQK];     // 17408 B
    __shared__ __align__(16) _Float16 Vt[HD][LVP];      // 17408 B
    __shared__ __align__(16) _Float16 Ps[8][16][LVP];   // 17408 B

    const int tid = threadIdx.x;
    const int wave = tid >> 6, lane = tid & 63;
    const int fl = lane & 15, quad = lane >> 4;
    const int hw = wave >> 1, mt = wave & 1;

    const int bd = blockIdx.x;
    const int c = bd & 255, sflip = bd >> 8;
    const int qt = sflip ? 63 - (c & 63) : (c & 63);
    const int kvh = (sflip << 2) + (c >> 6);
    const int h = kvh * 4 + hw;
    const int m0 = qt * FAM;
    const float scl2 = 0.12751879523209784f;  // HD^-0.5 * log2(e)

    // Q fragments: rows m0 + mt*16 + fl
    half8 qf[4];
    #pragma unroll
    for (int ks = 0; ks < 4; ++ks)
        qf[ks] = *(const half8*)(qkv
            + (size_t)(m0 + mt * 16 + fl) * QKV_DIM + h * HD + ks * 32 + quad * 8);

    // staging geometry (512 threads)
    const int vp = tid & 31, vg = tid >> 5;   // V: rows 2vp,2vp+1; d-group vg (0..15)

    float m_prev[4], l_prev[4];
    #pragma unroll
    for (int r = 0; r < 4; ++r) { m_prev[r] = -1e30f; l_prev[r] = 0.f; }
    floatx4 oacc[8] = {};

    const int tmax = (m0 + FAM - 1) / FAN;

    // prologue: tile 0 -> regs
    half8 kreg[2], vra, vrb;
    {
        #pragma unroll
        for (int l = 0; l < 2; ++l) {
            const int f = tid + l * 512;
            kreg[l] = *(const half8*)(qkv + (size_t)(f >> 4) * QKV_DIM
                       + K_OFF + kvh * HD + (f & 15) * 8);
        }
        const _Float16* v0p = qkv + (size_t)(2 * vp) * QKV_DIM
                              + V_OFF + kvh * HD + 8 * vg;
        vra = *(const half8*)v0p;
        vrb = *(const half8*)(v0p + QKV_DIM);
    }

    for (int t = 0; t <= tmax; ++t) {
        const int n0 = t * FAN;
        __syncthreads();   // (A) all waves done reading Ks/Vt of prev tile

        // regs -> LDS
        #pragma unroll
        for (int l = 0; l < 2; ++l) {
            const int f = tid + l * 512;
            *(half8*)&Ks[f >> 4][(f & 15) * 8] = kreg[l];
        }
        #pragma unroll
        for (int i = 0; i < 8; ++i) {
            half2v hh; hh[0] = vra[i]; hh[1] = vrb[i];
            *(half2v*)&Vt[8 * vg + i][2 * vp] = hh;
        }
        __syncthreads();   // (B) staged

        // issue next-tile loads (in flight across compute of tile t)
        if (t < tmax) {
            const int n1 = n0 + FAN;
            #pragma unroll
            for (int l = 0; l < 2; ++l) {
                const int f = tid + l * 512;
                kreg[l] = *(const half8*)(qkv + (size_t)(n1 + (f >> 4)) * QKV_DIM
                           + K_OFF + kvh * HD + (f & 15) * 8);
            }
            const _Float16* v1p = qkv + (size_t)(n1 + 2 * vp) * QKV_DIM
                                  + V_OFF + kvh * HD + 8 * vg;
            vra = *(const half8*)v1p;
            vrb = *(const half8*)(v1p + QKV_DIM);
        }

        // ---- QK^T: 1 m-tile x 4 n-tiles ----
        floatx4 sacc[4] = {};
        __builtin_amdgcn_s_setprio(1);
        #pragma unroll
        for (int ks = 0; ks < 4; ++ks)
            #pragma unroll
            for (int nt = 0; nt < 4; ++nt) {
                half8 bf = *(const half8*)&Ks[nt * 16 + fl][ks * 32 + quad * 8];
                sacc[nt] = __builtin_amdgcn_mfma_f32_16x16x32_f16(
                    qf[ks], bf, sacc[nt], 0, 0, 0);
            }
        __builtin_amdgcn_s_setprio(0);

        // ---- softmax (exp2 domain), rows mt*16 + quad*4 + r ----
        const bool diag = (t == tmax);
        float mx[4] = {-1e30f, -1e30f, -1e30f, -1e30f};
        #pragma unroll
        for (int nt = 0; nt < 4; ++nt)
            #pragma unroll
            for (int r = 0; r < 4; ++r) {
                float sv = sacc[nt][r] * scl2;
                if (diag && (n0 + nt * 16 + fl > m0 + mt * 16 + quad * 4 + r))
                    sv = -1e30f;
                sacc[nt][r] = sv;
                mx[r] = fmaxf(mx[r], sv);
            }
        #pragma unroll
        for (int r = 0; r < 4; ++r)
            #pragma unroll
            for (int o = 8; o; o >>= 1)
                mx[r] = fmaxf(mx[r], __shfl_xor(mx[r], o));

        // T13 defer-max: rescale only when some row grew past threshold
        bool grow = false;
        #pragma unroll
        for (int r = 0; r < 4; ++r) grow |= (mx[r] > m_prev[r] + THR_L2);
        if (__any(grow ? 1 : 0)) {
            #pragma unroll
            for (int r = 0; r < 4; ++r) {
                float nm = fmaxf(m_prev[r], mx[r]);
                float a = exp2f(m_prev[r] - nm);
                m_prev[r] = nm;
                l_prev[r] *= a;
                #pragma unroll
                for (int dt = 0; dt < 8; ++dt) oacc[dt][r] *= a;
            }
        }

        float rs[4] = {0.f, 0.f, 0.f, 0.f};
        #pragma unroll
        for (int nt = 0; nt < 4; ++nt)
            #pragma unroll
            for (int r = 0; r < 4; ++r) {
                float p = exp2f(sacc[nt][r] - m_prev[r]);
                rs[r] += p;
                Ps[wave][quad * 4 + r][nt * 16 + fl] = (_Float16)p;
            }
        #pragma unroll
        for (int r = 0; r < 4; ++r) {
            #pragma unroll
            for (int o = 8; o; o >>= 1) rs[r] += __shfl_xor(rs[r], o);
            l_prev[r] += rs[r];
        }

        // ---- PV (same-wave Ps; lgkmcnt orders write->read) ----
        __builtin_amdgcn_s_setprio(1);
        #pragma unroll
        for (int ks2 = 0; ks2 < 2; ++ks2) {
            half4v plo = *(const half4v*)&Ps[wave][fl][ks2 * 32 + quad * 8];
            half4v phi = *(const half4v*)&Ps[wave][fl][ks2 * 32 + quad * 8 + 4];
            half8 pa = __builtin_shufflevector(plo, phi, 0, 1, 2, 3, 4, 5, 6, 7);
            #pragma unroll
            for (int dt = 0; dt < 8; ++dt) {
                half4v vlo = *(const half4v*)&Vt[dt * 16 + fl][ks2 * 32 + quad * 8];
                half4v vhi = *(const half4v*)&Vt[dt * 16 + fl][ks2 * 32 + quad * 8 + 4];
                half8 vb = __builtin_shufflevector(vlo, vhi, 0, 1, 2, 3, 4, 5, 6, 7);
                oacc[dt] = __builtin_amdgcn_mfma_f32_16x16x32_f16(
                    pa, vb, oacc[dt], 0, 0, 0);
            }
        }
        __builtin_amdgcn_s_setprio(0);
    }

    float linv[4];
    #pragma unroll
    for (int r = 0; r < 4; ++r) linv[r] = 1.0f / l_prev[r];
    #pragma unroll
    for (int dt = 0; dt < 8; ++dt)
        #pragma unroll
        for (int r = 0; r < 4; ++r)
            attn[(size_t)(m0 + mt * 16 + quad * 4 + r) * NQHD
                 + h * HD + dt * 16 + fl] = (_Float16)(oacc[dt][r] * linv[r]);
}

// ---------------------------------------------------------------------------
extern "C" void kernel_launch(void* const* d_in, const int* in_sizes, int n_in,
                              void* d_out, int out_size, void* d_ws, size_t ws_size,
                              hipStream_t stream) {
    // inputs: positions, hidden_states, Wqkv, Wo, q_gamma, k_gamma, cos, sin
    const float* hidden = (const float*)d_in[1];
    const float* Wqkv   = (const float*)d_in[2];
    const float* Wo     = (const float*)d_in[3];
    const float* qg     = (const float*)d_in[4];
    const float* kg     = (const float*)d_in[5];
    const float* cosb   = (const float*)d_in[6];
    const float* sinb   = (const float*)d_in[7];
    float* out = (float*)d_out;

    // ws layout (67.1 MB total):
    //   buf0: h16 [2048][4096]     -> later attn16 [2048][4096] (same size)
    //   buf1: wT  [6144][4096]     -> later woT [4096][4096] (smaller)
    // qkv16 [2048][6144] fp16 lives in d_out; dead before gemm2 overwrites it.
    _Float16* buf0  = (_Float16*)d_ws;
    _Float16* wT    = buf0 + (size_t)S_LEN * HIDDEN;
    _Float16* qkv16 = (_Float16*)d_out;
    _Float16* attn16 = buf0;

    // 1) convert hidden -> fp16
    conv_f32_f16<<<(S_LEN * HIDDEN) / 2048, 256, 0, stream>>>(hidden, buf0);
    // 2) Wqkv [K=4096][N=6144] -> wT [6144][4096] fp16
    conv_w_transpose<<<dim3(QKV_DIM / 64, HIDDEN / 64), 256, 0, stream>>>(
        Wqkv, wT, QKV_DIM, HIDDEN);
    // 3) qkv16 = h16 @ wT^T  (256x256 8-phase, 24x8 = 192 blocks)
    gemm_8ph<_Float16, 256><<<dim3(QKV_DIM / 256, S_LEN / 256), 512, 0, stream>>>(
        buf0, wT, qkv16, HIDDEN, QKV_DIM);
    // 4) RMSNorm + RoPE in place (fp16), wave-per-head
    rmsnorm_rope_w<<<S_LEN, 256, 0, stream>>>(qkv16, qg, kg, cosb, sinb);
    // 5) GQA-shared flash attention (8-wave) -> attn16 (buf0; h16 dead)
    flash_attn_gqa8<<<dim3((S_LEN / FAM) * NKV), 512, 0, stream>>>(qkv16, attn16);
    // 6) Wo [4096][4096] -> woT fp16 (reuses wT slot; Wqkv16 dead)
    conv_w_transpose<<<dim3(HIDDEN / 64, NQHD / 64), 256, 0, stream>>>(
        Wo, wT, HIDDEN, NQHD);
    // 7) out = attn16 @ woT^T  (256x128 8-phase, 32x8 = 256 blocks, full fill)
    gemm_8ph<float, 128><<<dim3(HIDDEN / 128, S_LEN / 256), 512, 0, stream>>>(
        attn16, wT, out, NQHD, HIDDEN);
}